// Round 6
// baseline (227.065 us; speedup 1.0000x reference)
//
#include <hip/hip_runtime.h>

#define TOKENS 16384
#define EMB 4096
#define NEXP 64
#define BTOK 128   // tokens per block
#define BK 32      // k per staged chunk

// async global->LDS, 16B/lane; LDS dest = wave-uniform base + lane*16
__device__ __forceinline__ void gl_lds16(const float* g, void* lds) {
    __builtin_amdgcn_global_load_lds(
        (const __attribute__((address_space(1))) void*)g,
        (__attribute__((address_space(3))) void*)lds, 16, 0, 0);
}

// Kernel 1: partial GEMM, restructured after R5 showed LDS-return-bus bound
// (B/fma too high with both operands per-lane from LDS).
//   block = 256 thr = 4 waves; wave w = expert panel 16w..16w+15;
//   lane  = token slot; thread owns tokens {l, l+64} fully within its panel.
//   Per 4-k per thread: 2 per-lane X reads (64 unique addrs = data-floor
//   rate) + 16 WAVE-UNIFORM W reads (1 address -> pure broadcast, no
//   conflict possible) + 128 fmaf  => LDS demand ~0.65x VALU demand/CU.
// X staged by registers (coalesced global float4 -> LDS k-major [kq][tok];
// per-lane reads spread over 8 bank-quads). W staged via global_load_lds
// linear [e][kq] (uniform reads are bank-agnostic). K-split S: grid
// (128, S) -> 4 blocks/CU at S=8; S picked from ws_size at launch.
// Precision (R3-level): fp32 chain per 32-k chunk folded into fp64 run
// accumulators each chunk; err ~1e-7 << min top-2/3 gap ~1e-5.
template<int S>
__global__ __launch_bounds__(256, 4) void router_partial(
    const float* __restrict__ x, const float* __restrict__ W,
    float* __restrict__ ws)
{
    constexpr int KPER = EMB / S;
    constexpr int NCH  = KPER / BK;

    __shared__ float4 sX[BK / 4][BTOK];   // [kq][tok]  16 KB
    __shared__ float4 sW[NEXP][BK / 4];   // [e][kq]     8 KB

    const int t  = threadIdx.x;
    const int w  = t >> 6;          // wave = expert panel
    const int l  = t & 63;          // lane = token slot
    const int t0 = blockIdx.x * BTOK;
    const int kb = blockIdx.y * KPER;

    // x staging bases: round p -> token 32p + (t>>3), k-quad t&7 (coalesced:
    // 8 lanes read 128B contiguous per row)
    const float* gx[4];
#pragma unroll
    for (int p = 0; p < 4; ++p)
        gx[p] = x + (size_t)(t0 + 32 * p + (t >> 3)) * EMB + kb + 4 * (t & 7);

    // W staging: wave w, instr p: rows 8q..8q+7, q = 2w+p; lane -> row
    // 8q + (l>>3), k-quad l&7; LDS dest linear at &sW[8q][0]
    const float* gw[2];
#pragma unroll
    for (int p = 0; p < 2; ++p) {
        const int q = 2 * w + p;
        gw[p] = W + (size_t)(8 * q + (l >> 3)) * EMB + kb + 4 * (l & 7);
    }

    double run[2][16];
#pragma unroll
    for (int i = 0; i < 2; ++i)
#pragma unroll
        for (int j = 0; j < 16; ++j) run[i][j] = 0.0;

    // prologue: chunk 0 x -> regs
    float4 rx[4];
#pragma unroll
    for (int p = 0; p < 4; ++p) rx[p] = *reinterpret_cast<const float4*>(gx[p]);

    for (int kc = 0; kc < NCH; ++kc) {
        __syncthreads();              // previous chunk's readers done
        // write staged x (k-major), stage W chunk
#pragma unroll
        for (int p = 0; p < 4; ++p) sX[t & 7][32 * p + (t >> 3)] = rx[p];
#pragma unroll
        for (int p = 0; p < 2; ++p)
            gl_lds16(gw[p] + kc * BK, &sW[8 * (2 * w + p)][0]);
        __syncthreads();              // drains vmcnt: sX + sW ready

        // issue next chunk's x loads AFTER the barrier -> overlap compute
        if (kc + 1 < NCH) {
#pragma unroll
            for (int p = 0; p < 4; ++p)
                rx[p] = *reinterpret_cast<const float4*>(gx[p] + (kc + 1) * BK);
        }

        float ch[2][16];
#pragma unroll
        for (int i = 0; i < 2; ++i)
#pragma unroll
            for (int j = 0; j < 16; ++j) ch[i][j] = 0.f;

#pragma unroll 2
        for (int kq = 0; kq < BK / 4; ++kq) {
            const float4 xa0 = sX[kq][l];        // 64 unique addrs, 8 quads
            const float4 xa1 = sX[kq][64 + l];
#pragma unroll
            for (int j = 0; j < 16; ++j) {
                const float4 wv = sW[16 * w + j][kq];   // wave-uniform bcast
                ch[0][j] = fmaf(xa0.x, wv.x, ch[0][j]);
                ch[0][j] = fmaf(xa0.y, wv.y, ch[0][j]);
                ch[0][j] = fmaf(xa0.z, wv.z, ch[0][j]);
                ch[0][j] = fmaf(xa0.w, wv.w, ch[0][j]);
                ch[1][j] = fmaf(xa1.x, wv.x, ch[1][j]);
                ch[1][j] = fmaf(xa1.y, wv.y, ch[1][j]);
                ch[1][j] = fmaf(xa1.z, wv.z, ch[1][j]);
                ch[1][j] = fmaf(xa1.w, wv.w, ch[1][j]);
            }
        }
        // fold fp32 chunk chains into fp64 run accumulators
#pragma unroll
        for (int i = 0; i < 2; ++i)
#pragma unroll
            for (int j = 0; j < 16; ++j) run[i][j] += (double)ch[i][j];
    }

    // fp32 partials: ws[(s*64 + e)*TOKENS + token]; lanes coalesced
#pragma unroll
    for (int i = 0; i < 2; ++i)
#pragma unroll
        for (int j = 0; j < 16; ++j)
            ws[(size_t)(blockIdx.y * NEXP + 16 * w + j) * TOKENS
               + t0 + 64 * i + l] = (float)run[i][j];
}

// Kernel 2: combine splits in fp64 + bias, top-2, softmax.
// 4 threads/token (16-expert parts) for occupancy; merge via LDS.
template<int S>
__global__ __launch_bounds__(256) void reduce_topk(
    const float* __restrict__ ws, const float* __restrict__ b,
    float* __restrict__ out)
{
    __shared__ double sv[64][4][2];
    __shared__ int    si[64][4][2];
    const int t    = threadIdx.x;
    const int part = t & 3;
    const int slot = t >> 2;                 // 0..63
    const int tok  = blockIdx.x * 64 + slot;

    double v[16];
#pragma unroll
    for (int j = 0; j < 16; ++j) v[j] = 0.0;
    for (int s = 0; s < S; ++s)
#pragma unroll
        for (int j = 0; j < 16; ++j)
            v[j] += (double)ws[(size_t)((s << 6) + (part << 4) + j) * TOKENS + tok];
#pragma unroll
    for (int j = 0; j < 16; ++j) v[j] += (double)b[(part << 4) + j];

    double v1 = -1e300, v2 = -1e300; int i1 = 0, i2 = 0;
#pragma unroll
    for (int j = 0; j < 16; ++j) {
        const int e = (part << 4) + j;
        if (v[j] > v1)      { v2 = v1; i2 = i1; v1 = v[j]; i1 = e; }
        else if (v[j] > v2) { v2 = v[j]; i2 = e; }
    }
    sv[slot][part][0] = v1; sv[slot][part][1] = v2;
    si[slot][part][0] = i1; si[slot][part][1] = i2;
    __syncthreads();

    if (part == 0) {
        double m1 = -1e300, m2 = -1e300; int j1 = 0, j2 = 0;
        // scan parts ascending: strict > keeps lowest expert index on ties
#pragma unroll
        for (int p = 0; p < 4; ++p)
#pragma unroll
            for (int r = 0; r < 2; ++r) {
                const double vv = sv[slot][p][r]; const int ii = si[slot][p][r];
                if (vv > m1)      { m2 = m1; j2 = j1; m1 = vv; j1 = ii; }
                else if (vv > m2) { m2 = vv; j2 = ii; }
            }
        const float e2  = expf((float)(m2 - m1));   // <= 1
        const float inv = 1.0f / (1.0f + e2);
        out[2 * tok]     = (float)j1;
        out[2 * tok + 1] = (float)j2;
        out[2 * TOKENS + 2 * tok]     = inv;
        out[2 * TOKENS + 2 * tok + 1] = e2 * inv;
    }
}

extern "C" void kernel_launch(void* const* d_in, const int* in_sizes, int n_in,
                              void* d_out, int out_size, void* d_ws, size_t ws_size,
                              hipStream_t stream) {
    const float* x = (const float*)d_in[0];
    const float* W = (const float*)d_in[1];
    const float* b = (const float*)d_in[2];
    float* out = (float*)d_out;
    float* ws  = (float*)d_ws;

    const size_t per = (size_t)NEXP * TOKENS * sizeof(float);  // 4.19 MB/split
    if (ws_size >= 8 * per) {            // 33.6 MB -> 1024 blocks = 4/CU
        router_partial<8><<<dim3(TOKENS / BTOK, 8), 256, 0, stream>>>(x, W, ws);
        reduce_topk<8><<<dim3(TOKENS / 64), 256, 0, stream>>>(ws, b, out);
    } else if (ws_size >= 4 * per) {     // 16.8 MB -> 512 blocks = 2/CU
        router_partial<4><<<dim3(TOKENS / BTOK, 4), 256, 0, stream>>>(x, W, ws);
        reduce_topk<4><<<dim3(TOKENS / 64), 256, 0, stream>>>(ws, b, out);
    } else {                             // 8.4 MB (R4-proven) -> 256 blocks
        router_partial<2><<<dim3(TOKENS / BTOK, 2), 256, 0, stream>>>(x, W, ws);
        reduce_topk<2><<<dim3(TOKENS / 64), 256, 0, stream>>>(ws, b, out);
    }
}